// Round 4
// baseline (237.122 us; speedup 1.0000x reference)
//
#include <hip/hip_runtime.h>

#define B_DIM 4
#define T_DIM 4096
#define C_DIM 2048
#define KK 4
#define TT 16          // t-steps per tile; halo overhead = 3/16 (L2/L3-absorbed)
#define C4 (C_DIM / 4) // 512 float4 lanes across channels

#define NBLK  512      // persistent grid: 2 blocks/CU, 8 waves/CU
#define NTHREADS (NBLK * 256)
#define TOTAL_TILES (B_DIM * (T_DIM / TT) * C4)   // 524288 tile-threads
#define ITERS (TOTAL_TILES / NTHREADS)            // 4 tiles per thread

typedef float v4f __attribute__((ext_vector_type(4)));

// R4: persistent grid-stride experiment. Evidence: four one-shot variants
// (schedule/MLP/store-policy sweeps) all pinned at 2.55-2.62 TB/s, while the
// two known 6+ TB/s kernels on this chip (fillBufferAligned on this very
// trace: 6.5 TB/s @ 9% occupancy; m13 float4 copy: 6.29 TB/s) are both
// persistent grid-stride streamers. One-shot waves pay a load-latency ramp +
// store drain per ~35-VMEM lifetime and the single residency round has no
// backfill for stragglers (occupancy 54% = drain tail). Here each wave
// processes 4 tiles in sequence: continuous VMEM stream, next tile's loads
// overlap previous tile's store drain, fast waves absorb variance.
__global__ __launch_bounds__(256) void canonconv_kernel(
    const float* __restrict__ x,
    const float* __restrict__ w,
    const float* __restrict__ bias,
    float* __restrict__ out)
{
    const int tid = blockIdx.x * blockDim.x + threadIdx.x;

    #pragma unroll 1   // keep the tile loop rolled: persistent streaming body
    for (int iter = 0; iter < ITERS; ++iter) {
        const int idx   = tid + iter * NTHREADS;
        const int c4    = idx % C4;            // float4 channel group (lane-varying)
        const int tmp   = idx / C4;            // wave-uniform (64 lanes fit in one 512-c4 row)
        const int ttile = tmp % (T_DIM / TT);
        const int b     = tmp / (T_DIM / TT);
        const int t0    = ttile * TT;
        const int c     = c4 * 4;

        // --- weights/bias for this tile's channels
        const v4f* wv = (const v4f*)(w + (size_t)c * KK);
        const v4f a0 = wv[0];  // (w[c,0], w[c,1], w[c,2], w[c,3])
        const v4f a1 = wv[1];
        const v4f a2 = wv[2];
        const v4f a3 = wv[3];
        const v4f bv = *(const v4f*)(bias + c);

        const float* xb = x   + ((size_t)b * T_DIM) * C_DIM + c;
        float*       ob = out + ((size_t)b * T_DIM) * C_DIM + c;

        // --- halo (zeros before t=0; branch is wave-uniform)
        v4f xm3, xm2, xm1;
        const bool interior = (t0 != 0);
        if (interior) {
            xm3 = *(const v4f*)(xb + (size_t)(t0 - 3) * C_DIM);
            xm2 = *(const v4f*)(xb + (size_t)(t0 - 2) * C_DIM);
            xm1 = *(const v4f*)(xb + (size_t)(t0 - 1) * C_DIM);
        }

        // --- body loads (compiler interleaves with compute; schedule shape
        // proven perf-neutral in R0-R2, so let it keep VGPR low)
        v4f buf[TT];
        #pragma unroll
        for (int j = 0; j < TT; ++j) {
            buf[j] = *(const v4f*)(xb + (size_t)(t0 + j) * C_DIM);
        }

        if (!interior) {
            xm3 = (v4f)0.0f;
            xm2 = (v4f)0.0f;
            xm1 = (v4f)0.0f;
        }

        // --- per-tap coefficient vectors; x[t]-tap fused with residual (1+w)
        v4f tap0, tap1, tap2, tap3;
        tap0.x = a0.x; tap0.y = a1.x; tap0.z = a2.x; tap0.w = a3.x; // x[t-3]
        tap1.x = a0.y; tap1.y = a1.y; tap1.z = a2.y; tap1.w = a3.y; // x[t-2]
        tap2.x = a0.z; tap2.y = a1.z; tap2.z = a2.z; tap2.w = a3.z; // x[t-1]
        tap3.x = 1.0f + a0.w; tap3.y = 1.0f + a1.w; tap3.z = 1.0f + a2.w; tap3.w = 1.0f + a3.w;

        #pragma unroll
        for (int j = 0; j < TT; ++j) {
            const v4f xc = buf[j];
            v4f r;
            r.x = fmaf(xc.x, tap3.x, fmaf(xm1.x, tap2.x, fmaf(xm2.x, tap1.x, fmaf(xm3.x, tap0.x, bv.x))));
            r.y = fmaf(xc.y, tap3.y, fmaf(xm1.y, tap2.y, fmaf(xm2.y, tap1.y, fmaf(xm3.y, tap0.y, bv.y))));
            r.z = fmaf(xc.z, tap3.z, fmaf(xm1.z, tap2.z, fmaf(xm2.z, tap1.z, fmaf(xm3.z, tap0.z, bv.z))));
            r.w = fmaf(xc.w, tap3.w, fmaf(xm1.w, tap2.w, fmaf(xm2.w, tap1.w, fmaf(xm3.w, tap0.w, bv.w))));
            *(v4f*)(ob + (size_t)(t0 + j) * C_DIM) = r;
            xm3 = xm2;
            xm2 = xm1;
            xm1 = xc;
        }
    }
}

extern "C" void kernel_launch(void* const* d_in, const int* in_sizes, int n_in,
                              void* d_out, int out_size, void* d_ws, size_t ws_size,
                              hipStream_t stream) {
    const float* x    = (const float*)d_in[0];
    const float* w    = (const float*)d_in[1];
    const float* bias = (const float*)d_in[2];
    float* out = (float*)d_out;

    canonconv_kernel<<<NBLK, 256, 0, stream>>>(x, w, bias, out);
}